// Round 3
// baseline (275.661 us; speedup 1.0000x reference)
//
#include <hip/hip_runtime.h>

#define Bb 128
#define Cc 400
#define Ll 100
#define Pp 16

// ---------------------------------------------------------------------------
// Fused kernel, 4-way K-split for occupancy.
//
// Phase 1 (per block = one batch b, 64-channel tile): compute the 16x100
// weight matrix in LDS via closed form (see derivation below).
// Phase 2: thread quad (h=0..3) per channel row; each thread dot-products a
// quarter of the row (float4 chunks 7/6/6/6) against w for all 16 l, then a
// 2-round shfl_xor butterfly leaves each thread with 4 final outputs ->
// coalesced float4 store.
//
// Weight derivation (per b,l): q_j = 16*s + d*l + j (j in [0,d)), pos = q+8,
// t = (min(pos,1592)-8)/16, i0 = min(floor(t),98), fr = t-i0.
//   unclipped (q<1584): i0 = q>>4, fr = (q&15)/16
//   clipped   (q>=1584): i0 = 98, fr = 1 -> contributes 1.0 to w[99]
// w[i] = [sum_{i0_j==i}(1-fr_j) + sum_{i0_j==i-1}(fr_j)] / max(d,1),
// each piece a contiguous q-range -> triangular-number closed form.
// ---------------------------------------------------------------------------
__global__ __launch_bounds__(256) void TemporalPooling_fused_kernel(
    const float* __restrict__ x, const int* __restrict__ seg,
    float* __restrict__ out) {
  __shared__ float w[Ll * Pp];   // [i][l], 6.4 KiB

  const int b   = blockIdx.y;
  const int tid = threadIdx.x;

  const int s = seg[2 * b];
  const int e = seg[2 * b + 1];
  const int d = e - s;
  const float inv = 1.0f / (float)max(d, 1);

  // ---- phase 1: weights into LDS ----
  for (int idx = tid; idx < Ll * Pp; idx += 256) {
    const int i = idx >> 4;   // 0..99
    const int l = idx & 15;   // 0..15

    const int a  = 16 * s + d * l;   // q_0
    const int ad = a + d;            // q end (exclusive)

    float sum = 0.0f;

    const int base1 = 16 * i;
    {  // j with i0 == i : q in [16i,16i+16) ∩ [a,ad) ∩ [0,1584)
      const int lo = max(base1, a);
      const int hi = min(min(base1 + 16, ad), 1584);
      const int n = hi - lo;
      if (n > 0) {
        const int sq = (hi * (hi - 1) - lo * (lo - 1)) >> 1;
        sum += (float)n - (float)(sq - n * base1) * 0.0625f;
      }
    }
    {  // j with i0 == i-1 : q in [16(i-1),16i) ∩ [a,ad) ∩ [0,1584)
      const int base2 = base1 - 16;
      const int lo = max(base2, a);
      const int hi = min(min(base1, ad), 1584);
      const int n = hi - lo;
      if (n > 0) {
        const int sq = (hi * (hi - 1) - lo * (lo - 1)) >> 1;
        sum += (float)(sq - n * base2) * 0.0625f;
      }
    }
    if (i == Ll - 1) {  // clipped tail q >= 1584: fr=1 -> +1 each
      const int nclip = ad - max(a, 1584);
      if (nclip > 0) sum += (float)nclip;
    }

    w[idx] = sum * inv;
  }
  __syncthreads();

  // ---- phase 2: quarter-row dot products ----
  const int r = tid >> 2;        // 0..63  (channel within tile)
  const int h = tid & 3;         // quarter id
  const int c = blockIdx.x * 64 + r;
  if (c >= Cc) return;

  const int qstart = (h == 0) ? 0 : (7 + 6 * (h - 1));  // 0,7,13,19 (float4 units)
  const int qcnt   = (h == 0) ? 7 : 6;

  const float4* x4 =
      (const float4*)(x + ((size_t)b * Cc + c) * Ll) + qstart;
  float4 xv[7];
#pragma unroll
  for (int q = 0; q < 7; ++q)
    if (q < qcnt) xv[q] = x4[q];

  float acc[16];
#pragma unroll
  for (int l = 0; l < 16; ++l) acc[l] = 0.0f;

#pragma unroll
  for (int q = 0; q < 7; ++q) {
    if (q >= qcnt) break;
#pragma unroll
    for (int k = 0; k < 4; ++k) {
      const int i = (qstart + q) * 4 + k;
      const float xs = ((const float*)&xv[q])[k];
      // rotate l-pack order by h: conflicting quads hit different bank groups
#pragma unroll
      for (int p = 0; p < 4; ++p) {
        const int lp = ((p + h) & 3) * 4;
        const float4 wv = *(const float4*)&w[i * 16 + lp];
        acc[lp + 0] = fmaf(wv.x, xs, acc[lp + 0]);
        acc[lp + 1] = fmaf(wv.y, xs, acc[lp + 1]);
        acc[lp + 2] = fmaf(wv.z, xs, acc[lp + 2]);
        acc[lp + 3] = fmaf(wv.w, xs, acc[lp + 3]);
      }
    }
  }

  // ---- butterfly reduce across the quad (xor 1, then xor 2) ----
  const int hb0 = h & 1;
  const int hb1 = (h >> 1) & 1;

  float r1[8];
  {
    const int keep = hb0 * 8, send = (hb0 ^ 1) * 8;
#pragma unroll
    for (int k = 0; k < 8; ++k)
      r1[k] = acc[keep + k] + __shfl_xor(acc[send + k], 1);
  }
  float r2[4];
  {
    const int keep = hb1 * 4, send = (hb1 ^ 1) * 4;
#pragma unroll
    for (int k = 0; k < 4; ++k)
      r2[k] = r1[keep + k] + __shfl_xor(r1[send + k], 2);
  }

  const int lbase = hb0 * 8 + hb1 * 4;   // h=0:0, h=1:8, h=2:4, h=3:12
  float4* o4 = (float4*)(out + ((size_t)b * Cc + c) * Pp + lbase);
  *o4 = make_float4(r2[0], r2[1], r2[2], r2[3]);
}

extern "C" void kernel_launch(void* const* d_in, const int* in_sizes, int n_in,
                              void* d_out, int out_size, void* d_ws,
                              size_t ws_size, hipStream_t stream) {
  const float* x = (const float*)d_in[0];   // (128,400,100) fp32
  const int* seg = (const int*)d_in[1];     // (128,2) int32
  float* out = (float*)d_out;               // (128,400,16) fp32
  (void)d_ws; (void)ws_size;                // no workspace use

  dim3 grid((Cc + 63) / 64, Bb);            // (7, 128) = 896 blocks
  TemporalPooling_fused_kernel<<<grid, 256, 0, stream>>>(x, seg, out);
}

// Round 4
// 11.545 us; speedup vs baseline: 23.8765x; 23.8765x over previous
//
#include <hip/hip_runtime.h>

#define Bb 128
#define Cc 400
#define Ll 100
#define Pp 16

// ---------------------------------------------------------------------------
// Fused kernel, 4-way split over the OUTPUT (l) dimension for occupancy.
// (R3's K-split regressed 20x: lane-dependent register-array indices in the
//  butterfly sent acc[] to scratch — rule #20. This version has zero runtime
//  register indexing: each thread owns a static acc[4].)
//
// Phase 1 (per block = batch b, 64-channel tile): 16x100 weight matrix in LDS
// via closed form. Phase 2: thread (c, h): out[b,c,h*4..h*4+3] =
// sum_i x[b,c,i] * w[i][h*4..h*4+3]. Quad-mates (h=0..3) issue identical
// x addresses (HW same-address merge); w reads are ds_read_b128 at one base
// + immediate offsets, 4 distinct addrs/wave spanning banks 0..15 ->
// conflict-free. Stores: consecutive tids -> consecutive float4 -> 1KB/wave.
//
// Weight derivation (per b,l): q_j = 16*s + d*l + j (j in [0,d)), pos = q+8,
// t = (min(pos,1592)-8)/16, i0 = min(floor(t),98), fr = t-i0.
//   unclipped (q<1584): i0 = q>>4, fr = (q&15)/16
//   clipped   (q>=1584): i0 = 98, fr = 1 -> contributes 1.0 to w[99]
// w[i] = [sum_{i0_j==i}(1-fr_j) + sum_{i0_j==i-1}(fr_j)] / max(d,1),
// each piece a contiguous q-range -> triangular-number closed form.
// ---------------------------------------------------------------------------
__global__ __launch_bounds__(256) void TemporalPooling_fused_kernel(
    const float* __restrict__ x, const int* __restrict__ seg,
    float* __restrict__ out) {
  __shared__ float w[Ll * Pp];   // [i][l], 6.4 KiB

  const int b   = blockIdx.y;
  const int tid = threadIdx.x;

  const int s = seg[2 * b];
  const int e = seg[2 * b + 1];
  const int d = e - s;
  const float inv = 1.0f / (float)max(d, 1);

  // ---- phase 1: weights into LDS ----
  for (int idx = tid; idx < Ll * Pp; idx += 256) {
    const int i = idx >> 4;   // 0..99
    const int l = idx & 15;   // 0..15

    const int a  = 16 * s + d * l;   // q_0
    const int ad = a + d;            // q end (exclusive)

    float sum = 0.0f;

    const int base1 = 16 * i;
    {  // j with i0 == i : q in [16i,16i+16) ∩ [a,ad) ∩ [0,1584)
      const int lo = max(base1, a);
      const int hi = min(min(base1 + 16, ad), 1584);
      const int n = hi - lo;
      if (n > 0) {
        const int sq = (hi * (hi - 1) - lo * (lo - 1)) >> 1;
        sum += (float)n - (float)(sq - n * base1) * 0.0625f;
      }
    }
    {  // j with i0 == i-1 : q in [16(i-1),16i) ∩ [a,ad) ∩ [0,1584)
      const int base2 = base1 - 16;
      const int lo = max(base2, a);
      const int hi = min(min(base1, ad), 1584);
      const int n = hi - lo;
      if (n > 0) {
        const int sq = (hi * (hi - 1) - lo * (lo - 1)) >> 1;
        sum += (float)(sq - n * base2) * 0.0625f;
      }
    }
    if (i == Ll - 1) {  // clipped tail q >= 1584: fr=1 -> +1 each
      const int nclip = ad - max(a, 1584);
      if (nclip > 0) sum += (float)nclip;
    }

    w[idx] = sum * inv;
  }
  __syncthreads();

  // ---- phase 2: one thread per (channel, l-quad) ----
  const int r = tid >> 2;                 // 0..63 channel within tile
  const int h = tid & 3;                  // l-quad id
  const int c = blockIdx.x * 64 + r;
  if (c >= Cc) return;

  const float4* x4 = (const float4*)(x + ((size_t)b * Cc + c) * Ll);
  const float* wh = &w[h * 4];            // one base; i*64B immediate offsets

  float a0 = 0.0f, a1 = 0.0f, a2 = 0.0f, a3 = 0.0f;

#pragma unroll
  for (int q = 0; q < 25; ++q) {
    const float4 xc = x4[q];
#pragma unroll
    for (int k = 0; k < 4; ++k) {
      const int i = q * 4 + k;
      const float xs = (k == 0) ? xc.x : (k == 1) ? xc.y : (k == 2) ? xc.z
                                                                    : xc.w;
      const float4 wv = *(const float4*)&wh[i * 16];  // ds_read_b128 offset:i*64
      a0 = fmaf(wv.x, xs, a0);
      a1 = fmaf(wv.y, xs, a1);
      a2 = fmaf(wv.z, xs, a2);
      a3 = fmaf(wv.w, xs, a3);
    }
  }

  float4* o4 = (float4*)(out + ((size_t)b * Cc + c) * Pp + h * 4);
  *o4 = make_float4(a0, a1, a2, a3);
}

extern "C" void kernel_launch(void* const* d_in, const int* in_sizes, int n_in,
                              void* d_out, int out_size, void* d_ws,
                              size_t ws_size, hipStream_t stream) {
  const float* x = (const float*)d_in[0];   // (128,400,100) fp32
  const int* seg = (const int*)d_in[1];     // (128,2) int32
  float* out = (float*)d_out;               // (128,400,16) fp32
  (void)d_ws; (void)ws_size;                // no workspace use

  dim3 grid((Cc + 63) / 64, Bb);            // (7, 128) = 896 blocks
  TemporalPooling_fused_kernel<<<grid, 256, 0, stream>>>(x, seg, out);
}